// Round 15
// baseline (123.505 us; speedup 1.0000x reference)
//
#include <hip/hip_runtime.h>
#include <math.h>

#define CCH 4096
#define SP 891
#define NSL 32768

typedef __attribute__((ext_vector_type(8))) short short8;
typedef __attribute__((ext_vector_type(4))) float f32x4;

__device__ __forceinline__ unsigned int pack_bf2(float a, float b) {
  unsigned int ua = __builtin_bit_cast(unsigned int, a);
  unsigned int ub = __builtin_bit_cast(unsigned int, b);
  ua = (ua + 0x7fffu + ((ua >> 16) & 1u)) >> 16;
  ub = (ub + 0x7fffu + ((ub >> 16) & 1u)) >> 16;
  return ua | (ub << 16);
}

// ---------- setup: members + rowSid + cnt/off + inv0/inv1 (80 blocks x 64) ----------
__global__ void k_setup(const int* __restrict__ im0, const int* __restrict__ im1,
                        int* cnt0, int* off0, int* cnt1, int* off1,
                        int* mem0, int* mem1, int* rs0, int* rs1,
                        int* inv0, int* inv1) {
  int cb = blockIdx.x;
  int level = (cb >= 64) ? 1 : 0;
  int c = level ? cb - 64 : cb;
  const int* im = level ? im1 : im0;
  int* members = level ? mem1 : mem0;
  int* rs = level ? rs1 : rs0;
  int* inv = level ? inv1 : inv0;
  int lane = threadIdx.x;  // 64
  int lt = 0;
  for (int ch = lane; ch < CCH; ch += 64) lt += (im[ch] < c) ? 1 : 0;
  for (int o = 32; o; o >>= 1) lt += __shfl_xor(lt, o, 64);
  int base = lt;
  int cnt = 0;
  for (int chunk = 0; chunk < CCH; chunk += 64) {
    int ch = chunk + lane;
    bool m = (im[ch] == c);
    unsigned long long mk = __ballot(m);
    int pos = __popcll(mk & ((1ull << lane) - 1ull));
    if (m) members[base + cnt + pos] = ch;
    cnt += __popcll(mk);
  }
  int n = cnt;
  if (lane == 0) {
    if (level) { cnt1[c] = n; off1[c] = base; }
    else       { cnt0[c] = n; off0[c] = base; }
  }
  __syncthreads();
  for (int r = lane; r < n; r += 64) {
    #pragma unroll
    for (int q = 0; q < 8; q++) {
      int p = 8 * r + q;
      int b = p / n, j = p - b * n;
      int sid = b * CCH + members[base + j];
      rs[(size_t)(base + r) * 8 + q] = sid;
      inv[sid] = ((base + r) << 3) | q;   // (row,q) <-> sid bijection per level
    }
  }
}

// ---------- pack rep slices into fragment-major bf16 tables (B operands) ----------
__global__ void k_brep(const float* __restrict__ X,
    const int* __restrict__ off0, const int* __restrict__ off1,
    const int* __restrict__ rs0, const int* __restrict__ rs1,
    uint4* __restrict__ Bfrag0, uint4* __restrict__ Bfrag1) {
  int gid = blockIdx.x * 4 + (threadIdx.x >> 6);  // 0..39
  int l = threadIdx.x & 63;
  int lrow = l & 15, hi = l >> 4;
  int level = (gid >= 32) ? 1 : 0;
  int q = level ? (gid - 32) : (gid >> 2);
  int ct = level ? 0 : (gid & 3);
  int cc = ct * 16 + lrow;
  int base = level ? off1[cc] : off0[cc];
  int sid = (level ? rs1 : rs0)[(size_t)base * 8 + q];
  const float* ap = X + (size_t)sid * SP + hi * 8;
  uint4* dst = (level ? Bfrag1 + (size_t)(q * 28) * 64
                      : Bfrag0 + (size_t)((q * 4 + ct) * 28) * 64) + l;
  #pragma unroll 3
  for (int kc = 0; kc < 27; kc++) {
    float4 fa0 = *(const float4*)(ap + kc * 32);
    float4 fa1 = *(const float4*)(ap + kc * 32 + 4);
    uint4 ua;
    ua.x = pack_bf2(fa0.x, fa0.y); ua.y = pack_bf2(fa0.z, fa0.w);
    ua.z = pack_bf2(fa1.x, fa1.y); ua.w = pack_bf2(fa1.z, fa1.w);
    dst[kc * 64] = ua;
  }
  {
    float4 fa0, fa1;
    if (hi == 3) {
      fa0 = make_float4(ap[864], ap[865], ap[866], 0.f);
      fa1 = make_float4(0.f, 0.f, 0.f, 0.f);
    } else {
      fa0 = *(const float4*)(ap + 864);
      fa1 = *(const float4*)(ap + 868);
    }
    uint4 ua;
    ua.x = pack_bf2(fa0.x, fa0.y); ua.y = pack_bf2(fa0.z, fa0.w);
    ua.z = pack_bf2(fa1.x, fa1.y); ua.w = pack_bf2(fa1.z, fa1.w);
    dst[27 * 64] = ua;
  }
}

// ---------- pack2: SEQUENTIAL X read (sid order), bf16 pack, SCATTERED row writes ----------
// wave w handles slice sid: read 3.5KB sequential, write 1792B to Y0[(q0,r0)] and Y1[(q1,r1)]
__global__ __launch_bounds__(256) void k_pack2(const float* __restrict__ X,
    const int* __restrict__ inv0, const int* __restrict__ inv1,
    unsigned short* __restrict__ Y0, unsigned short* __restrict__ Y1,
    float* __restrict__ sn2) {
  const int w = threadIdx.x >> 6, l = threadIdx.x & 63;
  for (int sid = blockIdx.x * 4 + w; sid < NSL; sid += gridDim.x * 4) {
    const float* sp = X + (size_t)sid * SP;
    float4 v0, v1, v2, v3;
    {
      int el = 4 * l;
      v0 = *(const float4*)(sp + el);
      v1 = *(const float4*)(sp + 256 + el);
      v2 = *(const float4*)(sp + 512 + el);
      if (l <= 29)      v3 = *(const float4*)(sp + 768 + el);
      else if (l == 30) v3 = make_float4(sp[888], sp[889], sp[890], 0.f);
      else              v3 = make_float4(0.f, 0.f, 0.f, 0.f);
    }
    float s2 = v0.x * v0.x + v0.y * v0.y + v0.z * v0.z + v0.w * v0.w
             + v1.x * v1.x + v1.y * v1.y + v1.z * v1.z + v1.w * v1.w
             + v2.x * v2.x + v2.y * v2.y + v2.z * v2.z + v2.w * v2.w
             + v3.x * v3.x + v3.y * v3.y + v3.z * v3.z + v3.w * v3.w;
    for (int o = 32; o; o >>= 1) s2 += __shfl_xor(s2, o, 64);
    if (l == 0) sn2[sid] = s2;
    uint2 u0, u1, u2, u3;
    u0.x = pack_bf2(v0.x, v0.y); u0.y = pack_bf2(v0.z, v0.w);
    u1.x = pack_bf2(v1.x, v1.y); u1.y = pack_bf2(v1.z, v1.w);
    u2.x = pack_bf2(v2.x, v2.y); u2.y = pack_bf2(v2.z, v2.w);
    u3.x = pack_bf2(v3.x, v3.y); u3.y = pack_bf2(v3.z, v3.w);
    int i0 = inv0[sid], i1 = inv1[sid];
    unsigned short* d0 = Y0 + ((size_t)(i0 & 7) * CCH + (i0 >> 3)) * 896 + 4 * l;
    unsigned short* d1 = Y1 + ((size_t)(i1 & 7) * CCH + (i1 >> 3)) * 896 + 4 * l;
    *(uint2*)(d0) = u0;
    *(uint2*)(d0 + 256) = u1;
    *(uint2*)(d0 + 512) = u2;
    if (l < 32) *(uint2*)(d0 + 768) = u3;
    *(uint2*)(d1) = u0;
    *(uint2*)(d1 + 256) = u1;
    *(uint2*)(d1 + 512) = u2;
    if (l < 32) *(uint2*)(d1 + 768) = u3;
  }
}

// ---------- GEMM, both levels: contiguous Y rows -> LDS -> MFMA ----------
__global__ __launch_bounds__(256) void k_gemm_all(
    const unsigned short* __restrict__ Y0, const unsigned short* __restrict__ Y1,
    const uint4* __restrict__ Bfrag0, const uint4* __restrict__ Bfrag1,
    float* __restrict__ P8_0, float* __restrict__ P8_1) {
  __shared__ __align__(16) unsigned short T[16 * 904];
  __shared__ float4 Rf[256];
  const int q = blockIdx.y, tid = threadIdx.x;
  const int lev = blockIdx.x >> 8;
  const int rt = blockIdx.x & 255;
  const int l = tid & 63, w = tid >> 6;
  const int lrow = l & 15, hi = l >> 4;
  const unsigned short* Y = lev ? Y1 : Y0;
  // stage 16 consecutive rows (28 KB contiguous region)
  #pragma unroll
  for (int si = 0; si < 4; si++) {
    int i = w * 4 + si;
    const unsigned short* src = Y + ((size_t)q * CCH + rt * 16 + i) * 896;
    uint4 a0 = *(const uint4*)(src + l * 8);
    uint4 a1 = (l < 48) ? *(const uint4*)(src + 512 + l * 8) : make_uint4(0, 0, 0, 0);
    *(uint4*)(T + i * 904 + l * 8) = a0;
    if (l < 48) *(uint4*)(T + i * 904 + 512 + l * 8) = a1;
  }
  __syncthreads();
  const char* Abase = (const char*)T + lrow * 1808;
  if (!lev) {
    // L0: 16x64 tile; wave w owns col-frag w; depth-2 A / depth-4 B rotation
    const uint4* bq = Bfrag0 + (size_t)((q * 4 + w) * 28) * 64 + l;
    f32x4 acc = {0.f, 0.f, 0.f, 0.f};
    short8 A0 = *(const short8*)(Abase + (0 * 64 + hi * 16));
    short8 A1 = *(const short8*)(Abase + (1 * 64 + hi * 16));
    uint4 B0 = bq[0 * 64], B1 = bq[1 * 64], B2 = bq[2 * 64], B3 = bq[3 * 64];
    #pragma unroll
    for (int kc = 0; kc < 28; kc++) {
      short8 a = (kc & 1) ? A1 : A0;
      uint4 b = (kc & 3) == 0 ? B0 : (kc & 3) == 1 ? B1 : (kc & 3) == 2 ? B2 : B3;
      acc = __builtin_amdgcn_mfma_f32_16x16x32_bf16(a, __builtin_bit_cast(short8, b), acc, 0, 0, 0);
      if (kc + 2 < 28) {
        short8 an = *(const short8*)(Abase + ((kc + 2) * 64 + hi * 16));
        if (kc & 1) A1 = an; else A0 = an;
      }
      if (kc + 4 < 28) {
        uint4 bn = bq[(kc + 4) * 64];
        switch (kc & 3) { case 0: B0 = bn; break; case 1: B1 = bn; break;
                          case 2: B2 = bn; break; default: B3 = bn; }
      }
    }
    #pragma unroll
    for (int r = 0; r < 4; r++) {
      int row = rt * 16 + hi * 4 + r;
      P8_0[((size_t)q * CCH + row) * 64 + w * 16 + lrow] = acc[r];
    }
  } else {
    // L1: 16x16 tile; split-K over 4 waves + LDS reduce
    const uint4* bq = Bfrag1 + (size_t)(q * 28) * 64 + l;
    f32x4 acc = {0.f, 0.f, 0.f, 0.f};
    #pragma unroll
    for (int kk = 0; kk < 7; kk++) {
      int kc = w * 7 + kk;
      short8 a = *(const short8*)(Abase + (kc * 64 + hi * 16));
      uint4 b = bq[kc * 64];
      acc = __builtin_amdgcn_mfma_f32_16x16x32_bf16(a, __builtin_bit_cast(short8, b), acc, 0, 0, 0);
    }
    __syncthreads();
    Rf[w * 64 + l] = make_float4(acc[0], acc[1], acc[2], acc[3]);
    __syncthreads();
    if (w == 0) {
      float4 v0 = Rf[l], v1 = Rf[64 + l], v2 = Rf[128 + l], v3 = Rf[192 + l];
      float vr[4] = { v0.x + v1.x + v2.x + v3.x, v0.y + v1.y + v2.y + v3.y,
                      v0.z + v1.z + v2.z + v3.z, v0.w + v1.w + v2.w + v3.w };
      #pragma unroll
      for (int r = 0; r < 4; r++) {
        int row = rt * 16 + hi * 4 + r;
        P8_1[((size_t)q * CCH + row) * 16 + lrow] = vr[r];
      }
    }
  }
}

// ---------- per-cluster epilogue (512 threads), both levels in one dispatch ----------
template<int K>
__device__ __forceinline__ void fin_body(const float* __restrict__ P8,
    const float* __restrict__ sn2, const int* __restrict__ rs,
    const int* __restrict__ cnt, const int* __restrict__ off,
    double* __restrict__ clLoss, int c) {
  __shared__ float pcc[4096];
  __shared__ float red[512];
  __shared__ double redd[512];
  __shared__ float s_conc;
  const int n = cnt[c], base = off[c];
  const int tid = threadIdx.x;
  float rn0 = 0.f;
  #pragma unroll
  for (int qq = 0; qq < 8; qq++) rn0 += sn2[rs[(size_t)base * 8 + qq]];
  float t = 0.f;
  for (int r = tid; r < n; r += 512) {
    float pd = 0.f, rn = 0.f;
    #pragma unroll
    for (int qq = 0; qq < 8; qq++) {
      pd += P8[((size_t)qq * CCH + base + r) * K + c];
      rn += sn2[rs[(size_t)(base + r) * 8 + qq]];
    }
    pcc[r] = pd;
    if (r > 0) {
      float d2 = rn - 2.f * pd + rn0;
      t += (d2 > 0.f) ? sqrtf(d2) : 0.f;
    }
  }
  red[tid] = t; __syncthreads();
  for (int o = 256; o; o >>= 1) { if (tid < o) red[tid] += red[tid + o]; __syncthreads(); }
  if (tid == 0) s_conc = red[0] / ((float)n * logf((float)n + 10.f));
  __syncthreads();
  const float invc = 1.f / s_conc;
  const int wv = tid >> 6, lane = tid & 63;
  const int sub = (K == 64) ? 0 : (lane >> 4);
  const int cc = lane & (K - 1);
  constexpr int RPI = 8 * (64 / K);
  double acc = 0.0;
  for (int r = wv * (64 / K) + sub; r < n; r += RPI) {
    float s = 0.f;
    #pragma unroll
    for (int qq = 0; qq < 8; qq++) s += P8[((size_t)qq * CCH + base + r) * K + cc];
    float lg = s * invc;
    float m = lg;
    #pragma unroll
    for (int o = K / 2; o; o >>= 1) m = fmaxf(m, __shfl_xor(m, o, K));
    float e = expf(lg - m);
    float se = e;
    #pragma unroll
    for (int o = K / 2; o; o >>= 1) se += __shfl_xor(se, o, K);
    if (cc == 0) acc += (double)(m + logf(se)) - (double)(pcc[r] * invc);
  }
  redd[tid] = acc; __syncthreads();
  for (int o = 256; o; o >>= 1) { if (tid < o) redd[tid] += redd[tid + o]; __syncthreads(); }
  if (tid == 0) clLoss[c] = redd[0] / (double)n;
}

__global__ __launch_bounds__(512) void k_fin_all(const float* __restrict__ P8_0,
    const float* __restrict__ P8_1, const float* __restrict__ sn2,
    const int* __restrict__ rs0, const int* __restrict__ rs1,
    const int* __restrict__ cnt0, const int* __restrict__ off0,
    const int* __restrict__ cnt1, const int* __restrict__ off1,
    double* __restrict__ cl0, double* __restrict__ cl1) {
  if (blockIdx.x < 64) fin_body<64>(P8_0, sn2, rs0, cnt0, off0, cl0, blockIdx.x);
  else                 fin_body<16>(P8_1, sn2, rs1, cnt1, off1, cl1, blockIdx.x - 64);
}

// ---------- final scalars ----------
__global__ void k_final(const double* __restrict__ cl0, const double* __restrict__ cl1,
                        float* __restrict__ out) {
  if (threadIdx.x == 0) {
    double s0 = 0.0, s1 = 0.0;
    for (int i = 0; i < 64; i++) s0 += cl0[i];
    for (int i = 0; i < 16; i++) s1 += cl1[i];
    out[0] = (float)(s0 / 4096.0);
    out[1] = (float)(s1 / 8192.0);
  }
}

extern "C" void kernel_launch(void* const* d_in, const int* in_sizes, int n_in,
                              void* d_out, int out_size, void* d_ws, size_t ws_size,
                              hipStream_t stream) {
  const float* X = (const float*)d_in[0];
  const int* im0 = (const int*)d_in[1];
  const int* im1 = (const int*)d_in[2];
  float* out = (float*)d_out;

  char* w = (char*)d_ws;
  auto alloc = [&](size_t bytes) -> char* {
    char* p = w; w += (bytes + 255) & ~(size_t)255; return p;
  };
  int*    cnt0  = (int*)alloc(64 * 4);
  int*    off0  = (int*)alloc(64 * 4);
  int*    cnt1  = (int*)alloc(16 * 4);
  int*    off1  = (int*)alloc(16 * 4);
  int*    mem0  = (int*)alloc((size_t)CCH * 4);
  int*    mem1  = (int*)alloc((size_t)CCH * 4);
  int*    rs0   = (int*)alloc((size_t)CCH * 8 * 4);
  int*    rs1   = (int*)alloc((size_t)CCH * 8 * 4);
  int*    inv0  = (int*)alloc((size_t)NSL * 4);
  int*    inv1  = (int*)alloc((size_t)NSL * 4);
  float*  sn2   = (float*)alloc((size_t)NSL * 4);
  uint4*  Bfrag0 = (uint4*)alloc((size_t)32 * 28 * 64 * 16);
  uint4*  Bfrag1 = (uint4*)alloc((size_t)8 * 28 * 64 * 16);
  unsigned short* Y0 = (unsigned short*)alloc((size_t)8 * CCH * 896 * 2);  // 58.7 MB
  unsigned short* Y1 = (unsigned short*)alloc((size_t)8 * CCH * 896 * 2);  // 58.7 MB
  float*  P8_0  = (float*)alloc((size_t)8 * CCH * 64 * 4);
  float*  P8_1  = (float*)alloc((size_t)8 * CCH * 16 * 4);
  double* cl0   = (double*)alloc(64 * 8);
  double* cl1   = (double*)alloc(16 * 8);

  k_setup<<<80, 64, 0, stream>>>(im0, im1, cnt0, off0, cnt1, off1,
                                 mem0, mem1, rs0, rs1, inv0, inv1);
  k_brep<<<10, 256, 0, stream>>>(X, off0, off1, rs0, rs1, Bfrag0, Bfrag1);
  k_pack2<<<2048, 256, 0, stream>>>(X, inv0, inv1, Y0, Y1, sn2);
  k_gemm_all<<<dim3(512, 8), 256, 0, stream>>>(Y0, Y1, Bfrag0, Bfrag1, P8_0, P8_1);
  k_fin_all<<<80, 512, 0, stream>>>(P8_0, P8_1, sn2, rs0, rs1, cnt0, off0, cnt1, off1, cl0, cl1);
  k_final<<<1, 64, 0, stream>>>(cl0, cl1, out);
}

// Round 16
// 102.025 us; speedup vs baseline: 1.2105x; 1.2105x over previous
//
#include <hip/hip_runtime.h>
#include <math.h>

#define CCH 4096
#define SP 891
#define NSL 32768

typedef __attribute__((ext_vector_type(8))) short short8;
typedef __attribute__((ext_vector_type(4))) float f32x4;

__device__ __forceinline__ unsigned int pack_bf2(float a, float b) {
  unsigned int ua = __builtin_bit_cast(unsigned int, a);
  unsigned int ub = __builtin_bit_cast(unsigned int, b);
  ua = (ua + 0x7fffu + ((ua >> 16) & 1u)) >> 16;
  ub = (ub + 0x7fffu + ((ub >> 16) & 1u)) >> 16;
  return ua | (ub << 16);
}

// ---------- setup: members + rowSid + cnt/off + inv1 (80 blocks x 64) ----------
__global__ void k_setup(const int* __restrict__ im0, const int* __restrict__ im1,
                        int* cnt0, int* off0, int* cnt1, int* off1,
                        int* mem0, int* mem1, int* rs0, int* rs1, int* inv1) {
  int cb = blockIdx.x;
  int level = (cb >= 64) ? 1 : 0;
  int c = level ? cb - 64 : cb;
  const int* im = level ? im1 : im0;
  int* members = level ? mem1 : mem0;
  int* rs = level ? rs1 : rs0;
  int lane = threadIdx.x;  // 64
  int lt = 0;
  for (int ch = lane; ch < CCH; ch += 64) lt += (im[ch] < c) ? 1 : 0;
  for (int o = 32; o; o >>= 1) lt += __shfl_xor(lt, o, 64);
  int base = lt;
  int cnt = 0;
  for (int chunk = 0; chunk < CCH; chunk += 64) {
    int ch = chunk + lane;
    bool m = (im[ch] == c);
    unsigned long long mk = __ballot(m);
    int pos = __popcll(mk & ((1ull << lane) - 1ull));
    if (m) members[base + cnt + pos] = ch;
    cnt += __popcll(mk);
  }
  int n = cnt;
  if (lane == 0) {
    if (level) { cnt1[c] = n; off1[c] = base; }
    else       { cnt0[c] = n; off0[c] = base; }
  }
  __syncthreads();
  for (int r = lane; r < n; r += 64) {
    #pragma unroll
    for (int q = 0; q < 8; q++) {
      int p = 8 * r + q;
      int b = p / n, j = p - b * n;
      int sid = b * CCH + members[base + j];
      rs[(size_t)(base + r) * 8 + q] = sid;
      if (level) inv1[sid] = ((base + r) << 3) | q;   // row1<<3 | q1 (bijection)
    }
  }
}

// ---------- pack rep slices into fragment-major bf16 tables (B operands) ----------
__global__ void k_brep(const float* __restrict__ X,
    const int* __restrict__ off0, const int* __restrict__ off1,
    const int* __restrict__ rs0, const int* __restrict__ rs1,
    uint4* __restrict__ Bfrag0, uint4* __restrict__ Bfrag1) {
  int gid = blockIdx.x * 4 + (threadIdx.x >> 6);  // 0..39
  int l = threadIdx.x & 63;
  int lrow = l & 15, hi = l >> 4;
  int level = (gid >= 32) ? 1 : 0;
  int q = level ? (gid - 32) : (gid >> 2);
  int ct = level ? 0 : (gid & 3);
  int cc = ct * 16 + lrow;
  int base = level ? off1[cc] : off0[cc];
  int sid = (level ? rs1 : rs0)[(size_t)base * 8 + q];
  const float* ap = X + (size_t)sid * SP + hi * 8;
  uint4* dst = (level ? Bfrag1 + (size_t)(q * 28) * 64
                      : Bfrag0 + (size_t)((q * 4 + ct) * 28) * 64) + l;
  #pragma unroll 3
  for (int kc = 0; kc < 27; kc++) {
    float4 fa0 = *(const float4*)(ap + kc * 32);
    float4 fa1 = *(const float4*)(ap + kc * 32 + 4);
    uint4 ua;
    ua.x = pack_bf2(fa0.x, fa0.y); ua.y = pack_bf2(fa0.z, fa0.w);
    ua.z = pack_bf2(fa1.x, fa1.y); ua.w = pack_bf2(fa1.z, fa1.w);
    dst[kc * 64] = ua;
  }
  {
    float4 fa0, fa1;
    if (hi == 3) {
      fa0 = make_float4(ap[864], ap[865], ap[866], 0.f);
      fa1 = make_float4(0.f, 0.f, 0.f, 0.f);
    } else {
      fa0 = *(const float4*)(ap + 864);
      fa1 = *(const float4*)(ap + 868);
    }
    uint4 ua;
    ua.x = pack_bf2(fa0.x, fa0.y); ua.y = pack_bf2(fa0.z, fa0.w);
    ua.z = pack_bf2(fa1.x, fa1.y); ua.w = pack_bf2(fa1.z, fa1.w);
    dst[27 * 64] = ua;
  }
}

// ---------- single-gather GEMM: L0 tile (rt,q0); both levels from one LDS tile ----------
// L1 computed 16x128 (all 8 q of Bfrag1), per-row keep the q1(sid) column block.
__global__ __launch_bounds__(256) void k_gemm_all(const float* __restrict__ X,
    const int* __restrict__ rs0, const int* __restrict__ inv1,
    const uint4* __restrict__ Bfrag0, const uint4* __restrict__ Bfrag1,
    float* __restrict__ P8_0, float* __restrict__ P8_1, float* __restrict__ sn2) {
  __shared__ __align__(16) unsigned short T[16 * 904];   // 28.9 KB, 1808B rows
  __shared__ int s_sid[16];
  __shared__ int s_inv[16];
  const int rt = blockIdx.x, q = blockIdx.y, tid = threadIdx.x;
  const int l = tid & 63, w = tid >> 6;
  const int lrow = l & 15, hi = l >> 4;
  if (tid < 16) {
    int sid = rs0[(size_t)(rt * 16 + tid) * 8 + q];
    s_sid[tid] = sid;
    s_inv[tid] = inv1[sid];
  }
  __syncthreads();
  // B prefetch (L2-resident tables): 3 streams x depth-4
  const uint4* bq0 = Bfrag0 + (size_t)((q * 4 + w) * 28) * 64 + l;
  const uint4* bqa = Bfrag1 + (size_t)((w * 2) * 28) * 64 + l;
  const uint4* bqb = Bfrag1 + (size_t)((w * 2 + 1) * 28) * 64 + l;
  uint4 C0 = bq0[0 * 64], C1 = bq0[1 * 64], C2 = bq0[2 * 64], C3 = bq0[3 * 64];
  uint4 D0 = bqa[0 * 64], D1 = bqa[1 * 64], D2 = bqa[2 * 64], D3 = bqa[3 * 64];
  uint4 E0 = bqb[0 * 64], E1 = bqb[1 * 64], E2 = bqb[2 * 64], E3 = bqb[3 * 64];
  // gather: wave w loads slices w*4..w*4+3 whole (1KB-granule wave-loads)
  float4 sv[4][4];
  #pragma unroll
  for (int si = 0; si < 4; si++) {
    const float* sp = X + (size_t)s_sid[w * 4 + si] * SP;
    #pragma unroll
    for (int t = 0; t < 4; t++) {
      int el = t * 256 + 4 * l;
      float4 v;
      if (t < 3)           v = *(const float4*)(sp + el);
      else if (l <= 29)    v = *(const float4*)(sp + el);
      else if (l == 30)    v = make_float4(sp[888], sp[889], sp[890], 0.f);
      else                 v = make_float4(0.f, 0.f, 0.f, 0.f);
      sv[si][t] = v;
    }
  }
  // sn2 + LDS rows
  #pragma unroll
  for (int si = 0; si < 4; si++) {
    int sid = s_sid[w * 4 + si];
    float s2 = 0.f;
    #pragma unroll
    for (int t = 0; t < 4; t++) {
      float4 v = sv[si][t];
      s2 += v.x * v.x + v.y * v.y + v.z * v.z + v.w * v.w;
    }
    for (int o = 32; o; o >>= 1) s2 += __shfl_xor(s2, o, 64);
    if (l == 0) sn2[sid] = s2;
    unsigned short* Trow = T + (w * 4 + si) * 904;
    #pragma unroll
    for (int t = 0; t < 4; t++) {
      float4 v = sv[si][t];
      uint2 u;
      u.x = pack_bf2(v.x, v.y); u.y = pack_bf2(v.z, v.w);
      if (t < 3 || l < 32) *(uint2*)(Trow + t * 256 + 4 * l) = u;
    }
  }
  __syncthreads();
  // compute: shared A; 3 B streams (L0 colfrag w; L1 colfrags 2w, 2w+1)
  const char* Abase = (const char*)T + lrow * 1808;
  f32x4 acc0 = {0.f, 0.f, 0.f, 0.f};
  f32x4 accA = {0.f, 0.f, 0.f, 0.f};
  f32x4 accB = {0.f, 0.f, 0.f, 0.f};
  short8 A0 = *(const short8*)(Abase + (0 * 64 + hi * 16));
  short8 A1 = *(const short8*)(Abase + (1 * 64 + hi * 16));
#define BSTEP(BQ, B0, B1, B2, B3, ACC) { \
    uint4 b_ = (kc & 3) == 0 ? B0 : (kc & 3) == 1 ? B1 : (kc & 3) == 2 ? B2 : B3; \
    ACC = __builtin_amdgcn_mfma_f32_16x16x32_bf16(a, __builtin_bit_cast(short8, b_), ACC, 0, 0, 0); \
    if (kc + 4 < 28) { \
      uint4 bn_ = BQ[(kc + 4) * 64]; \
      switch (kc & 3) { case 0: B0 = bn_; break; case 1: B1 = bn_; break; \
                        case 2: B2 = bn_; break; default: B3 = bn_; } \
    } }
  #pragma unroll
  for (int kc = 0; kc < 28; kc++) {
    short8 a = (kc & 1) ? A1 : A0;
    BSTEP(bq0, C0, C1, C2, C3, acc0)
    BSTEP(bqa, D0, D1, D2, D3, accA)
    BSTEP(bqb, E0, E1, E2, E3, accB)
    if (kc + 2 < 28) {
      short8 an = *(const short8*)(Abase + ((kc + 2) * 64 + hi * 16));
      if (kc & 1) A1 = an; else A0 = an;
    }
  }
#undef BSTEP
  // L0 write
  #pragma unroll
  for (int r = 0; r < 4; r++) {
    int row = rt * 16 + hi * 4 + r;
    P8_0[((size_t)q * CCH + row) * 64 + w * 16 + lrow] = acc0[r];
  }
  // L1 write: keep cols matching each row's q1
  const int f0 = w * 2, f1 = w * 2 + 1;
  #pragma unroll
  for (int r = 0; r < 4; r++) {
    int inv = s_inv[hi * 4 + r];
    int q1 = inv & 7, row1 = inv >> 3;
    if (q1 == f0)      P8_1[((size_t)q1 * CCH + row1) * 16 + lrow] = accA[r];
    else if (q1 == f1) P8_1[((size_t)q1 * CCH + row1) * 16 + lrow] = accB[r];
  }
}

// ---------- per-cluster epilogue (512 threads), both levels in one dispatch ----------
template<int K>
__device__ __forceinline__ void fin_body(const float* __restrict__ P8,
    const float* __restrict__ sn2, const int* __restrict__ rs,
    const int* __restrict__ cnt, const int* __restrict__ off,
    double* __restrict__ clLoss, int c) {
  __shared__ float pcc[4096];
  __shared__ float red[512];
  __shared__ double redd[512];
  __shared__ float s_conc;
  const int n = cnt[c], base = off[c];
  const int tid = threadIdx.x;
  float rn0 = 0.f;
  #pragma unroll
  for (int qq = 0; qq < 8; qq++) rn0 += sn2[rs[(size_t)base * 8 + qq]];
  float t = 0.f;
  for (int r = tid; r < n; r += 512) {
    float pd = 0.f, rn = 0.f;
    #pragma unroll
    for (int qq = 0; qq < 8; qq++) {
      pd += P8[((size_t)qq * CCH + base + r) * K + c];
      rn += sn2[rs[(size_t)(base + r) * 8 + qq]];
    }
    pcc[r] = pd;
    if (r > 0) {
      float d2 = rn - 2.f * pd + rn0;
      t += (d2 > 0.f) ? sqrtf(d2) : 0.f;
    }
  }
  red[tid] = t; __syncthreads();
  for (int o = 256; o; o >>= 1) { if (tid < o) red[tid] += red[tid + o]; __syncthreads(); }
  if (tid == 0) s_conc = red[0] / ((float)n * logf((float)n + 10.f));
  __syncthreads();
  const float invc = 1.f / s_conc;
  const int wv = tid >> 6, lane = tid & 63;
  const int sub = (K == 64) ? 0 : (lane >> 4);
  const int cc = lane & (K - 1);
  constexpr int RPI = 8 * (64 / K);
  double acc = 0.0;
  for (int r = wv * (64 / K) + sub; r < n; r += RPI) {
    float s = 0.f;
    #pragma unroll
    for (int qq = 0; qq < 8; qq++) s += P8[((size_t)qq * CCH + base + r) * K + cc];
    float lg = s * invc;
    float m = lg;
    #pragma unroll
    for (int o = K / 2; o; o >>= 1) m = fmaxf(m, __shfl_xor(m, o, K));
    float e = expf(lg - m);
    float se = e;
    #pragma unroll
    for (int o = K / 2; o; o >>= 1) se += __shfl_xor(se, o, K);
    if (cc == 0) acc += (double)(m + logf(se)) - (double)(pcc[r] * invc);
  }
  redd[tid] = acc; __syncthreads();
  for (int o = 256; o; o >>= 1) { if (tid < o) redd[tid] += redd[tid + o]; __syncthreads(); }
  if (tid == 0) clLoss[c] = redd[0] / (double)n;
}

__global__ __launch_bounds__(512) void k_fin_all(const float* __restrict__ P8_0,
    const float* __restrict__ P8_1, const float* __restrict__ sn2,
    const int* __restrict__ rs0, const int* __restrict__ rs1,
    const int* __restrict__ cnt0, const int* __restrict__ off0,
    const int* __restrict__ cnt1, const int* __restrict__ off1,
    double* __restrict__ cl0, double* __restrict__ cl1) {
  if (blockIdx.x < 64) fin_body<64>(P8_0, sn2, rs0, cnt0, off0, cl0, blockIdx.x);
  else                 fin_body<16>(P8_1, sn2, rs1, cnt1, off1, cl1, blockIdx.x - 64);
}

// ---------- final scalars ----------
__global__ void k_final(const double* __restrict__ cl0, const double* __restrict__ cl1,
                        float* __restrict__ out) {
  if (threadIdx.x == 0) {
    double s0 = 0.0, s1 = 0.0;
    for (int i = 0; i < 64; i++) s0 += cl0[i];
    for (int i = 0; i < 16; i++) s1 += cl1[i];
    out[0] = (float)(s0 / 4096.0);
    out[1] = (float)(s1 / 8192.0);
  }
}

extern "C" void kernel_launch(void* const* d_in, const int* in_sizes, int n_in,
                              void* d_out, int out_size, void* d_ws, size_t ws_size,
                              hipStream_t stream) {
  const float* X = (const float*)d_in[0];
  const int* im0 = (const int*)d_in[1];
  const int* im1 = (const int*)d_in[2];
  float* out = (float*)d_out;

  char* w = (char*)d_ws;
  auto alloc = [&](size_t bytes) -> char* {
    char* p = w; w += (bytes + 255) & ~(size_t)255; return p;
  };
  int*    cnt0  = (int*)alloc(64 * 4);
  int*    off0  = (int*)alloc(64 * 4);
  int*    cnt1  = (int*)alloc(16 * 4);
  int*    off1  = (int*)alloc(16 * 4);
  int*    mem0  = (int*)alloc((size_t)CCH * 4);
  int*    mem1  = (int*)alloc((size_t)CCH * 4);
  int*    rs0   = (int*)alloc((size_t)CCH * 8 * 4);
  int*    rs1   = (int*)alloc((size_t)CCH * 8 * 4);
  int*    inv1  = (int*)alloc((size_t)NSL * 4);
  float*  sn2   = (float*)alloc((size_t)NSL * 4);
  uint4*  Bfrag0 = (uint4*)alloc((size_t)32 * 28 * 64 * 16);
  uint4*  Bfrag1 = (uint4*)alloc((size_t)8 * 28 * 64 * 16);
  float*  P8_0  = (float*)alloc((size_t)8 * CCH * 64 * 4);
  float*  P8_1  = (float*)alloc((size_t)8 * CCH * 16 * 4);
  double* cl0   = (double*)alloc(64 * 8);
  double* cl1   = (double*)alloc(16 * 8);

  k_setup<<<80, 64, 0, stream>>>(im0, im1, cnt0, off0, cnt1, off1,
                                 mem0, mem1, rs0, rs1, inv1);
  k_brep<<<10, 256, 0, stream>>>(X, off0, off1, rs0, rs1, Bfrag0, Bfrag1);
  k_gemm_all<<<dim3(256, 8), 256, 0, stream>>>(X, rs0, inv1, Bfrag0, Bfrag1,
                                               P8_0, P8_1, sn2);
  k_fin_all<<<80, 512, 0, stream>>>(P8_0, P8_1, sn2, rs0, rs1, cnt0, off0, cnt1, off1, cl0, cl1);
  k_final<<<1, 64, 0, stream>>>(cl0, cl1, out);
}